// Round 2
// baseline (1778.440 us; speedup 1.0000x reference)
//
#include <hip/hip_runtime.h>
#include <math.h>

#define NT 2048
#define HS 64
#define HNN 256
#define NSTEPS 1000
#define TSTEP 0.01f

typedef unsigned short u16;
typedef __attribute__((ext_vector_type(8))) short bf16x8;
typedef __attribute__((ext_vector_type(4))) float f32x4;

// ws layout (float offsets)
#define OFF_PINV 0         // 64*64
#define OFF_LAM  4096      // 64
#define OFF_B2P  4160      // 64
#define OFF_Q    4224      // 2*64
#define OFF_W2P  4352      // 64*256
#define OFF_LP   20736     // 1000*64 lam_pow[k][i]
#define OFF_LT   84736     // 64*1000 lamT[i][k]
#define OFF_HT   148736    // 256*2048 hT[j][c]; later reused for Yh/Yl bf16 frags
#define OFF_Y0   673024    // 64*2048
// end: 804096 floats

// RNE f32 -> bf16 split: x ~= hi + lo (each bf16), err ~ 2^-18 |x|
__device__ inline void bsplit(float x, u16& hi, u16& lo) {
    unsigned u = __float_as_uint(x);
    unsigned r = (u + 0x7FFFu + ((u >> 16) & 1u)) >> 16;
    hi = (u16)r;
    float xh = __uint_as_float(r << 16);
    float d = x - xh;
    unsigned v = __float_as_uint(d);
    unsigned s = (v + 0x7FFFu + ((v >> 16) & 1u)) >> 16;
    lo = (u16)s;
}

// ---------------- setup: Gauss-Jordan inverse of P, lam, Q, b2p ----------------
__global__ __launch_bounds__(256) void k_setup(const float* __restrict__ P,
                                               const float* __restrict__ D,
                                               const float* __restrict__ lm_w,
                                               const float* __restrict__ l2_b,
                                               float* __restrict__ ws) {
    __shared__ float Aug[64][130];
    __shared__ int s_piv;
    int tid = threadIdx.x;

    for (int idx = tid; idx < 64 * 128; idx += 256) {
        int r = idx >> 7, c = idx & 127;
        Aug[r][c] = (c < 64) ? P[r * 64 + c] : ((c - 64) == r ? 1.f : 0.f);
    }
    __syncthreads();

    for (int j = 0; j < 64; ++j) {
        if (tid < 64) {
            float v = (tid >= j) ? fabsf(Aug[tid][j]) : -1.f;
            int pi = tid;
            for (int off = 32; off; off >>= 1) {
                float ov = __shfl_xor(v, off);
                int opi = __shfl_xor(pi, off);
                if (ov > v) { v = ov; pi = opi; }
            }
            if (tid == 0) s_piv = pi;
        }
        __syncthreads();
        int piv = s_piv;
        if (piv != j && tid < 128) {
            float a = Aug[j][tid], b = Aug[piv][tid];
            Aug[j][tid] = b; Aug[piv][tid] = a;
        }
        __syncthreads();
        float pr = 1.0f / Aug[j][j];
        __syncthreads();
        if (tid < 128) Aug[j][tid] *= pr;
        __syncthreads();
        int r = tid >> 2;
        int c0 = (tid & 3) * 32;
        float f = Aug[r][j];
        __syncthreads();
        if (r != j) {
            #pragma unroll
            for (int c = 0; c < 32; ++c) Aug[r][c0 + c] -= f * Aug[j][c0 + c];
        }
        __syncthreads();
    }

    for (int idx = tid; idx < 4096; idx += 256) {
        int r = idx >> 6, c = idx & 63;
        ws[OFF_PINV + idx] = Aug[r][64 + c];
    }
    if (tid < 64) ws[OFF_LAM + tid] = 1.0f - TSTEP * expf(D[tid]);
    if (tid < 64) {
        float s = 0.f;
        for (int r = 0; r < 64; ++r) s += Aug[tid][64 + r] * l2_b[r];
        ws[OFF_B2P + tid] = s;
    }
    if (tid < 128) {
        int a = tid >> 6, i = tid & 63;
        float s = 0.f;
        for (int r = 0; r < 64; ++r) s += lm_w[a * 64 + r] * P[r * 64 + i];
        ws[OFF_Q + tid] = s;
    }
}

// ---------------- W2p = Pinv @ l2_w  (64 x 256) ----------------
__global__ __launch_bounds__(256) void k_w2p(const float* __restrict__ l2_w,
                                             float* __restrict__ ws) {
    int idx = blockIdx.x * 256 + threadIdx.x;
    int i = idx >> 8, j = idx & 255;
    const float* Pinv = ws + OFF_PINV + i * 64;
    float a0 = 0, a1 = 0, a2 = 0, a3 = 0;
    #pragma unroll
    for (int r = 0; r < 64; r += 4) {
        a0 = fmaf(Pinv[r],     l2_w[r * 256 + j],       a0);
        a1 = fmaf(Pinv[r + 1], l2_w[(r + 1) * 256 + j], a1);
        a2 = fmaf(Pinv[r + 2], l2_w[(r + 2) * 256 + j], a2);
        a3 = fmaf(Pinv[r + 3], l2_w[(r + 3) * 256 + j], a3);
    }
    ws[OFF_W2P + idx] = (a0 + a1) + (a2 + a3);
}

// ---------------- lam powers ----------------
__global__ __launch_bounds__(256) void k_lampow(float* __restrict__ ws) {
    int idx = blockIdx.x * 256 + threadIdx.x;
    if (idx >= NSTEPS * 64) return;
    int k = idx >> 6, i = idx & 63;
    float l = ws[OFF_LAM + i];
    float p = exp2f((float)k * log2f(l));
    ws[OFF_LP + idx] = p;
    ws[OFF_LT + i * NSTEPS + k] = p;
}

// ---------------- hT[j][c] = relu(target[c] . l1_w[j] + l1_b[j]) ----------------
__global__ __launch_bounds__(256) void k_ht(const float* __restrict__ target,
                                            const float* __restrict__ l1_w,
                                            const float* __restrict__ l1_b,
                                            float* __restrict__ ws) {
    int idx = blockIdx.x * 256 + threadIdx.x;
    int j = idx >> 11, c = idx & 2047;
    const float2 t = ((const float2*)target)[c];
    float h = fmaf(l1_w[2 * j], t.x, fmaf(l1_w[2 * j + 1], t.y, l1_b[j]));
    ws[OFF_HT + j * NT + c] = fmaxf(h, 0.f);
}

// ---------------- y0[i][c] = sum_j W2p[i][j] hT[j][c] + b2p[i] ----------------
__global__ __launch_bounds__(256) void k_y0(float* __restrict__ ws) {
    int idx = blockIdx.x * 256 + threadIdx.x;
    int i = idx >> 11, c = idx & 2047;
    const float* W2pi = ws + OFF_W2P + i * 256;
    const float* hT = ws + OFF_HT;
    float a0 = ws[OFF_B2P + i], a1 = 0, a2 = 0, a3 = 0;
    #pragma unroll 8
    for (int j = 0; j < 256; j += 4) {
        a0 = fmaf(W2pi[j],     hT[j * NT + c],       a0);
        a1 = fmaf(W2pi[j + 1], hT[(j + 1) * NT + c], a1);
        a2 = fmaf(W2pi[j + 2], hT[(j + 2) * NT + c], a2);
        a3 = fmaf(W2pi[j + 3], hT[(j + 3) * NT + c], a3);
    }
    ws[OFF_Y0 + i * NT + c] = (a0 + a1) + (a2 + a3);
}

// ---------------- y0 -> bf16 hi/lo fragments over dead hT region ----------------
// Layout: [ct(128)][kt(2)][lane(64)][j(8)]; elem = y0[kt*32+(lane>>4)*8+j][ct*16+(lane&15)]
__global__ __launch_bounds__(256) void k_yfrag(float* __restrict__ ws) {
    int idx = blockIdx.x * 256 + threadIdx.x;   // 16384
    int lane = idx & 63;
    int kt = (idx >> 6) & 1;
    int ct = idx >> 7;
    int c = ct * 16 + (lane & 15);
    int i0 = kt * 32 + (lane >> 4) * 8;
    const float* y0 = ws + OFF_Y0;
    u16* YH = (u16*)(ws + OFF_HT);
    u16* YL = YH + 131072;
    bf16x8 vh, vl;
    #pragma unroll
    for (int j = 0; j < 8; ++j) {
        u16 h, lo;
        bsplit(y0[(i0 + j) * NT + c], h, lo);
        vh[j] = (short)h;
        vl[j] = (short)lo;
    }
    int off = ((ct * 2 + kt) * 64 + lane);
    *(bf16x8*)(YH + off * 8) = vh;
    *(bf16x8*)(YL + off * 8) = vl;
}

// ---------------- main: hidden[k] = (P diag(lam^k)) @ y0 via split-bf16 MFMA ----------------
__global__ __launch_bounds__(256, 2) void k_hidden(const float* __restrict__ P,
                                                   const float* __restrict__ ws,
                                                   float* __restrict__ hidden) {
    int k = blockIdx.y;
    int tid = threadIdx.x;
    int wid = tid >> 6, lane = tid & 63;
    int l15 = lane & 15, lg = lane >> 4;

    const u16* YH = (const u16*)(ws + OFF_HT);
    const u16* YL = YH + 131072;
    const float* lp = ws + OFF_LP + k * 64;

    // B fragments for this wave's 64 columns
    int cbase = blockIdx.x * 256 + wid * 64;
    int ct0 = cbase >> 4;
    bf16x8 bh[4][2], bl[4][2];
    #pragma unroll
    for (int ct = 0; ct < 4; ++ct)
        #pragma unroll
        for (int kt = 0; kt < 2; ++kt) {
            int off = (((ct0 + ct) * 2 + kt) * 64 + lane) * 8;
            bh[ct][kt] = *(const bf16x8*)(YH + off);
            bl[ct][kt] = *(const bf16x8*)(YL + off);
        }

    // A fragments (P * lam^k) computed in-registers
    bf16x8 ah[4][2], al[4][2];
    #pragma unroll
    for (int rt = 0; rt < 4; ++rt) {
        int r = rt * 16 + l15;
        #pragma unroll
        for (int kt = 0; kt < 2; ++kt) {
            int i0 = kt * 32 + lg * 8;
            #pragma unroll
            for (int j = 0; j < 8; ++j) {
                float v = P[r * 64 + i0 + j] * lp[i0 + j];
                u16 h, lo;
                bsplit(v, h, lo);
                ah[rt][kt][j] = (short)h;
                al[rt][kt][j] = (short)lo;
            }
        }
    }

    float* outb = hidden + (size_t)k * 64 * NT + cbase + l15;
    int rowl = lg * 4;
    #pragma unroll 1
    for (int rt = 0; rt < 4; ++rt) {
        #pragma unroll
        for (int ct = 0; ct < 4; ++ct) {
            f32x4 acc = {0.f, 0.f, 0.f, 0.f};
            #pragma unroll
            for (int kt = 0; kt < 2; ++kt) {
                acc = __builtin_amdgcn_mfma_f32_16x16x32_bf16(ah[rt][kt], bh[ct][kt], acc, 0, 0, 0);
                acc = __builtin_amdgcn_mfma_f32_16x16x32_bf16(ah[rt][kt], bl[ct][kt], acc, 0, 0, 0);
                acc = __builtin_amdgcn_mfma_f32_16x16x32_bf16(al[rt][kt], bh[ct][kt], acc, 0, 0, 0);
                acc = __builtin_amdgcn_mfma_f32_16x16x32_bf16(al[rt][kt], bl[ct][kt], acc, 0, 0, 0);
            }
            #pragma unroll
            for (int reg = 0; reg < 4; ++reg)
                outb[(size_t)(rt * 16 + rowl + reg) * NT + ct * 16] = acc[reg];
        }
    }
}

// ---------------- acts ----------------
__global__ __launch_bounds__(256) void k_acts(const float* __restrict__ ws,
                                              const float* __restrict__ lm_b,
                                              float* __restrict__ actions) {
    int c = blockIdx.x;
    int tid = threadIdx.x;
    __shared__ float u[128];
    if (tid < 128) {
        int a = tid >> 6, i = tid & 63;
        u[tid] = ws[OFF_Q + a * 64 + i] * ws[OFF_Y0 + i * NT + c];
    }
    __syncthreads();
    float b0 = lm_b[0], b1 = lm_b[1];
    const float* lamT = ws + OFF_LT;
    for (int k = tid; k < NSTEPS; k += 256) {
        float a0 = b0, a1 = b1;
        #pragma unroll 8
        for (int i = 0; i < 64; ++i) {
            float v = lamT[i * NSTEPS + k];
            a0 = fmaf(u[i], v, a0);
            a1 = fmaf(u[64 + i], v, a1);
        }
        actions[c * 2000 + k] = tanhf(a0);
        actions[c * 2000 + 1000 + k] = tanhf(a1);
    }
}

extern "C" void kernel_launch(void* const* d_in, const int* in_sizes, int n_in,
                              void* d_out, int out_size, void* d_ws, size_t ws_size,
                              hipStream_t stream) {
    const float* target = (const float*)d_in[0];
    const float* D      = (const float*)d_in[1];
    const float* P      = (const float*)d_in[2];
    const float* l1_w   = (const float*)d_in[3];
    const float* l1_b   = (const float*)d_in[4];
    const float* l2_w   = (const float*)d_in[5];
    const float* l2_b   = (const float*)d_in[6];
    const float* lm_w   = (const float*)d_in[7];
    const float* lm_b   = (const float*)d_in[8];
    float* ws = (float*)d_ws;
    float* actions = (float*)d_out;                  // 2048*2*1000
    float* hidden  = (float*)d_out + 4096000;        // 1000*64*2048

    hipLaunchKernelGGL(k_setup,  dim3(1),       dim3(256), 0, stream, P, D, lm_w, l2_b, ws);
    hipLaunchKernelGGL(k_w2p,    dim3(64),      dim3(256), 0, stream, l2_w, ws);
    hipLaunchKernelGGL(k_lampow, dim3(250),     dim3(256), 0, stream, ws);
    hipLaunchKernelGGL(k_ht,     dim3(2048),    dim3(256), 0, stream, target, l1_w, l1_b, ws);
    hipLaunchKernelGGL(k_y0,     dim3(512),     dim3(256), 0, stream, ws);
    hipLaunchKernelGGL(k_yfrag,  dim3(64),      dim3(256), 0, stream, ws);
    hipLaunchKernelGGL(k_hidden, dim3(8, 1000), dim3(256), 0, stream, P, ws, hidden);
    hipLaunchKernelGGL(k_acts,   dim3(2048),    dim3(256), 0, stream, ws, lm_b, actions);
}

// Round 3
// 279.567 us; speedup vs baseline: 6.3614x; 6.3614x over previous
//
#include <hip/hip_runtime.h>
#include <math.h>

#define NT 2048
#define HS 64
#define HNN 256
#define NSTEPS 1000
#define TSTEP 0.01f

typedef unsigned short u16;
typedef __attribute__((ext_vector_type(8))) short bf16x8;
typedef __attribute__((ext_vector_type(4))) float f32x4;

// ws layout (float offsets)
#define OFF_PINV 0         // 64*64
#define OFF_LAM  4096      // 64
#define OFF_B2P  4160      // 64
#define OFF_Q    4224      // 2*64
#define OFF_W2P  4352      // 64*256
#define OFF_LP   20736     // 1000*64 lam_pow[k][i]
#define OFF_LT   84736     // 64*1000 lamT[i][k]
#define OFF_HT   148736    // 256*2048 hT[j][c]; later reused for Yh/Yl bf16 frags
#define OFF_Y0   673024    // 64*2048
// end: 804096 floats

// RNE f32 -> bf16 split: x ~= hi + lo (each bf16), err ~ 2^-18 |x|
__device__ inline void bsplit(float x, u16& hi, u16& lo) {
    unsigned u = __float_as_uint(x);
    unsigned r = (u + 0x7FFFu + ((u >> 16) & 1u)) >> 16;
    hi = (u16)r;
    float xh = __uint_as_float(r << 16);
    float d = x - xh;
    unsigned v = __float_as_uint(d);
    unsigned s = (v + 0x7FFFu + ((v >> 16) & 1u)) >> 16;
    lo = (u16)s;
}

// ---------------- setup: Gauss-Jordan inverse of P, lam, Q, b2p ----------------
__global__ __launch_bounds__(256) void k_setup(const float* __restrict__ P,
                                               const float* __restrict__ D,
                                               const float* __restrict__ lm_w,
                                               const float* __restrict__ l2_b,
                                               float* __restrict__ ws) {
    __shared__ float Aug[64][130];
    __shared__ int s_piv;
    int tid = threadIdx.x;

    for (int idx = tid; idx < 64 * 128; idx += 256) {
        int r = idx >> 7, c = idx & 127;
        Aug[r][c] = (c < 64) ? P[r * 64 + c] : ((c - 64) == r ? 1.f : 0.f);
    }
    __syncthreads();

    for (int j = 0; j < 64; ++j) {
        if (tid < 64) {
            float v = (tid >= j) ? fabsf(Aug[tid][j]) : -1.f;
            int pi = tid;
            for (int off = 32; off; off >>= 1) {
                float ov = __shfl_xor(v, off);
                int opi = __shfl_xor(pi, off);
                if (ov > v) { v = ov; pi = opi; }
            }
            if (tid == 0) s_piv = pi;
        }
        __syncthreads();
        int piv = s_piv;
        if (piv != j && tid < 128) {
            float a = Aug[j][tid], b = Aug[piv][tid];
            Aug[j][tid] = b; Aug[piv][tid] = a;
        }
        __syncthreads();
        float pr = 1.0f / Aug[j][j];
        __syncthreads();
        if (tid < 128) Aug[j][tid] *= pr;
        __syncthreads();
        int r = tid >> 2;
        int c0 = (tid & 3) * 32;
        float f = Aug[r][j];
        __syncthreads();
        if (r != j) {
            #pragma unroll
            for (int c = 0; c < 32; ++c) Aug[r][c0 + c] -= f * Aug[j][c0 + c];
        }
        __syncthreads();
    }

    for (int idx = tid; idx < 4096; idx += 256) {
        int r = idx >> 6, c = idx & 63;
        ws[OFF_PINV + idx] = Aug[r][64 + c];
    }
    if (tid < 64) ws[OFF_LAM + tid] = 1.0f - TSTEP * expf(D[tid]);
    if (tid < 64) {
        float s = 0.f;
        for (int r = 0; r < 64; ++r) s += Aug[tid][64 + r] * l2_b[r];
        ws[OFF_B2P + tid] = s;
    }
    if (tid < 128) {
        int a = tid >> 6, i = tid & 63;
        float s = 0.f;
        for (int r = 0; r < 64; ++r) s += lm_w[a * 64 + r] * P[r * 64 + i];
        ws[OFF_Q + tid] = s;
    }
}

// ---------------- W2p = Pinv @ l2_w  (64 x 256) ----------------
__global__ __launch_bounds__(256) void k_w2p(const float* __restrict__ l2_w,
                                             float* __restrict__ ws) {
    int idx = blockIdx.x * 256 + threadIdx.x;
    int i = idx >> 8, j = idx & 255;
    const float* Pinv = ws + OFF_PINV + i * 64;
    float a0 = 0, a1 = 0, a2 = 0, a3 = 0;
    #pragma unroll
    for (int r = 0; r < 64; r += 4) {
        a0 = fmaf(Pinv[r],     l2_w[r * 256 + j],       a0);
        a1 = fmaf(Pinv[r + 1], l2_w[(r + 1) * 256 + j], a1);
        a2 = fmaf(Pinv[r + 2], l2_w[(r + 2) * 256 + j], a2);
        a3 = fmaf(Pinv[r + 3], l2_w[(r + 3) * 256 + j], a3);
    }
    ws[OFF_W2P + idx] = (a0 + a1) + (a2 + a3);
}

// ---------------- lam powers ----------------
__global__ __launch_bounds__(256) void k_lampow(float* __restrict__ ws) {
    int idx = blockIdx.x * 256 + threadIdx.x;
    if (idx >= NSTEPS * 64) return;
    int k = idx >> 6, i = idx & 63;
    float l = ws[OFF_LAM + i];
    float p = exp2f((float)k * log2f(l));
    ws[OFF_LP + idx] = p;
    ws[OFF_LT + i * NSTEPS + k] = p;
}

// ---------------- hT[j][c] = relu(target[c] . l1_w[j] + l1_b[j]) ----------------
__global__ __launch_bounds__(256) void k_ht(const float* __restrict__ target,
                                            const float* __restrict__ l1_w,
                                            const float* __restrict__ l1_b,
                                            float* __restrict__ ws) {
    int idx = blockIdx.x * 256 + threadIdx.x;
    int j = idx >> 11, c = idx & 2047;
    const float2 t = ((const float2*)target)[c];
    float h = fmaf(l1_w[2 * j], t.x, fmaf(l1_w[2 * j + 1], t.y, l1_b[j]));
    ws[OFF_HT + j * NT + c] = fmaxf(h, 0.f);
}

// ---------------- y0[i][c] = sum_j W2p[i][j] hT[j][c] + b2p[i] ----------------
__global__ __launch_bounds__(256) void k_y0(float* __restrict__ ws) {
    int idx = blockIdx.x * 256 + threadIdx.x;
    int i = idx >> 11, c = idx & 2047;
    const float* W2pi = ws + OFF_W2P + i * 256;
    const float* hT = ws + OFF_HT;
    float a0 = ws[OFF_B2P + i], a1 = 0, a2 = 0, a3 = 0;
    #pragma unroll 8
    for (int j = 0; j < 256; j += 4) {
        a0 = fmaf(W2pi[j],     hT[j * NT + c],       a0);
        a1 = fmaf(W2pi[j + 1], hT[(j + 1) * NT + c], a1);
        a2 = fmaf(W2pi[j + 2], hT[(j + 2) * NT + c], a2);
        a3 = fmaf(W2pi[j + 3], hT[(j + 3) * NT + c], a3);
    }
    ws[OFF_Y0 + i * NT + c] = (a0 + a1) + (a2 + a3);
}

// ---------------- y0 -> bf16 hi/lo fragments over dead hT region ----------------
// Layout: [ct(128)][kt(2)][lane(64)][j(8)]; elem = y0[kt*32+(lane>>4)*8+j][ct*16+(lane&15)]
__global__ __launch_bounds__(256) void k_yfrag(float* __restrict__ ws) {
    int idx = blockIdx.x * 256 + threadIdx.x;   // 16384
    int lane = idx & 63;
    int kt = (idx >> 6) & 1;
    int ct = idx >> 7;
    int c = ct * 16 + (lane & 15);
    int i0 = kt * 32 + (lane >> 4) * 8;
    const float* y0 = ws + OFF_Y0;
    u16* YH = (u16*)(ws + OFF_HT);
    u16* YL = YH + 131072;
    bf16x8 vh, vl;
    #pragma unroll
    for (int j = 0; j < 8; ++j) {
        u16 h, lo;
        bsplit(y0[(i0 + j) * NT + c], h, lo);
        vh[j] = (short)h;
        vl[j] = (short)lo;
    }
    int off = ((ct * 2 + kt) * 64 + lane);
    *(bf16x8*)(YH + off * 8) = vh;
    *(bf16x8*)(YL + off * 8) = vl;
}

// ---------------- main: hidden[k] = (P diag(lam^k)) @ y0 via split-bf16 MFMA ----------------
// One block per k, all 2048 columns. LDS-staged coalesced stores.
#define LDS_STRIDE 260
__global__ __launch_bounds__(256, 2) void k_hidden(const float* __restrict__ P,
                                                   const float* __restrict__ ws,
                                                   float* __restrict__ hidden) {
    int k = blockIdx.x;
    int tid = threadIdx.x;
    int wid = tid >> 6, lane = tid & 63;
    int l15 = lane & 15, lg = lane >> 4;

    __shared__ float stage[64 * LDS_STRIDE];

    const u16* YH = (const u16*)(ws + OFF_HT);
    const u16* YL = YH + 131072;
    const float* lp = ws + OFF_LP + k * 64;

    // A fragments (P * lam^k), built ONCE per block, reused for all 2048 cols
    bf16x8 ah[4][2], al[4][2];
    #pragma unroll
    for (int rt = 0; rt < 4; ++rt) {
        int r = rt * 16 + l15;
        #pragma unroll
        for (int kt = 0; kt < 2; ++kt) {
            int i0 = kt * 32 + lg * 8;
            #pragma unroll
            for (int j = 0; j < 8; ++j) {
                float v = P[r * 64 + i0 + j] * lp[i0 + j];
                u16 h, lo;
                bsplit(v, h, lo);
                ah[rt][kt][j] = (short)h;
                al[rt][kt][j] = (short)lo;
            }
        }
    }

    float* outk = hidden + (size_t)k * 64 * NT;

    #pragma unroll 1
    for (int chunk = 0; chunk < 8; ++chunk) {
        int ct0 = (chunk * 256 + wid * 64) >> 4;
        // B fragments for this wave's 64 columns of the chunk
        bf16x8 bh[4][2], bl[4][2];
        #pragma unroll
        for (int ct = 0; ct < 4; ++ct)
            #pragma unroll
            for (int kt = 0; kt < 2; ++kt) {
                int off = (((ct0 + ct) * 2 + kt) * 64 + lane) * 8;
                bh[ct][kt] = *(const bf16x8*)(YH + off);
                bl[ct][kt] = *(const bf16x8*)(YL + off);
            }
        #pragma unroll
        for (int rt = 0; rt < 4; ++rt) {
            #pragma unroll
            for (int ct = 0; ct < 4; ++ct) {
                f32x4 acc = {0.f, 0.f, 0.f, 0.f};
                #pragma unroll
                for (int kt = 0; kt < 2; ++kt) {
                    acc = __builtin_amdgcn_mfma_f32_16x16x32_bf16(ah[rt][kt], bh[ct][kt], acc, 0, 0, 0);
                    acc = __builtin_amdgcn_mfma_f32_16x16x32_bf16(al[rt][kt], bh[ct][kt], acc, 0, 0, 0);
                    acc = __builtin_amdgcn_mfma_f32_16x16x32_bf16(ah[rt][kt], bl[ct][kt], acc, 0, 0, 0);
                }
                int col = wid * 64 + ct * 16 + l15;
                #pragma unroll
                for (int reg = 0; reg < 4; ++reg)
                    stage[(rt * 16 + lg * 4 + reg) * LDS_STRIDE + col] = acc[reg];
            }
        }
        __syncthreads();
        // coalesced dump: each wave stores full rows (1KB per instruction)
        #pragma unroll
        for (int t = 0; t < 16; ++t) {
            int idx = tid + t * 256;          // 0..4095
            int r = idx >> 6, c4 = idx & 63;
            float4 v = *(const float4*)&stage[r * LDS_STRIDE + (c4 << 2)];
            *(float4*)(outk + (size_t)r * NT + chunk * 256 + (c4 << 2)) = v;
        }
        __syncthreads();
    }
}

// ---------------- acts ----------------
__global__ __launch_bounds__(256) void k_acts(const float* __restrict__ ws,
                                              const float* __restrict__ lm_b,
                                              float* __restrict__ actions) {
    int c = blockIdx.x;
    int tid = threadIdx.x;
    __shared__ float u[128];
    if (tid < 128) {
        int a = tid >> 6, i = tid & 63;
        u[tid] = ws[OFF_Q + a * 64 + i] * ws[OFF_Y0 + i * NT + c];
    }
    __syncthreads();
    float b0 = lm_b[0], b1 = lm_b[1];
    const float* lamT = ws + OFF_LT;
    for (int k = tid; k < NSTEPS; k += 256) {
        float a0 = b0, a1 = b1;
        #pragma unroll 8
        for (int i = 0; i < 64; ++i) {
            float v = lamT[i * NSTEPS + k];
            a0 = fmaf(u[i], v, a0);
            a1 = fmaf(u[64 + i], v, a1);
        }
        actions[c * 2000 + k] = tanhf(a0);
        actions[c * 2000 + 1000 + k] = tanhf(a1);
    }
}

extern "C" void kernel_launch(void* const* d_in, const int* in_sizes, int n_in,
                              void* d_out, int out_size, void* d_ws, size_t ws_size,
                              hipStream_t stream) {
    const float* target = (const float*)d_in[0];
    const float* D      = (const float*)d_in[1];
    const float* P      = (const float*)d_in[2];
    const float* l1_w   = (const float*)d_in[3];
    const float* l1_b   = (const float*)d_in[4];
    const float* l2_w   = (const float*)d_in[5];
    const float* l2_b   = (const float*)d_in[6];
    const float* lm_w   = (const float*)d_in[7];
    const float* lm_b   = (const float*)d_in[8];
    float* ws = (float*)d_ws;
    float* actions = (float*)d_out;                  // 2048*2*1000
    float* hidden  = (float*)d_out + 4096000;        // 1000*64*2048

    hipLaunchKernelGGL(k_setup,  dim3(1),    dim3(256), 0, stream, P, D, lm_w, l2_b, ws);
    hipLaunchKernelGGL(k_w2p,    dim3(64),   dim3(256), 0, stream, l2_w, ws);
    hipLaunchKernelGGL(k_lampow, dim3(250),  dim3(256), 0, stream, ws);
    hipLaunchKernelGGL(k_ht,     dim3(2048), dim3(256), 0, stream, target, l1_w, l1_b, ws);
    hipLaunchKernelGGL(k_y0,     dim3(512),  dim3(256), 0, stream, ws);
    hipLaunchKernelGGL(k_yfrag,  dim3(64),   dim3(256), 0, stream, ws);
    hipLaunchKernelGGL(k_hidden, dim3(1000), dim3(256), 0, stream, P, ws, hidden);
    hipLaunchKernelGGL(k_acts,   dim3(2048), dim3(256), 0, stream, ws, lm_b, actions);
}